// Round 2
// baseline (440.079 us; speedup 1.0000x reference)
//
#include <hip/hip_runtime.h>

#define BATCH 4
#define CCH 512
#define NPIX 4096
#define NGRP 32
#define GSZ 16
#define GN_EPS 1e-6f

typedef __attribute__((ext_vector_type(8))) short short8;
typedef __attribute__((ext_vector_type(8))) unsigned short ushort8;
typedef __attribute__((ext_vector_type(4))) unsigned short ushort4v;
typedef __attribute__((ext_vector_type(4))) float f32x4;

__device__ inline unsigned short f2bf(float f) {
  unsigned u = __float_as_uint(f);
  unsigned r = u + 0x7fffu + ((u >> 16) & 1u);
  return (unsigned short)(r >> 16);
}

#define GLOAD16(g, l)                                                         \
  __builtin_amdgcn_global_load_lds(                                           \
      (__attribute__((address_space(1))) void*)(g),                           \
      (__attribute__((address_space(3))) void*)(l), 16, 0, 0)

// ---------------- GroupNorm stats: one block per (b, group) ----------------
__global__ __launch_bounds__(256) void gn_stats(const float* __restrict__ x,
                                                float* __restrict__ stats) {
  int bg = blockIdx.x;  // b*32 + g ; group data is contiguous 16*4096 floats
  const f32x4* base = (const f32x4*)(x + (size_t)bg * (GSZ * NPIX));
  float s = 0.f, ss = 0.f;
  const int n4 = GSZ * NPIX / 4;  // 16384
  for (int i = threadIdx.x; i < n4; i += 256) {
    f32x4 v = base[i];
    s += v.x + v.y + v.z + v.w;
    ss += v.x * v.x + v.y * v.y + v.z * v.z + v.w * v.w;
  }
  for (int off = 32; off > 0; off >>= 1) {
    s += __shfl_xor(s, off, 64);
    ss += __shfl_xor(ss, off, 64);
  }
  __shared__ float rs[4], rss[4];
  int lane = threadIdx.x & 63, wid = threadIdx.x >> 6;
  if (lane == 0) { rs[wid] = s; rss[wid] = ss; }
  __syncthreads();
  if (threadIdx.x == 0) {
    float S = rs[0] + rs[1] + rs[2] + rs[3];
    float SS = rss[0] + rss[1] + rss[2] + rss[3];
    const float inv = 1.f / (float)(GSZ * NPIX);
    float mean = S * inv;
    float var = SS * inv - mean * mean;
    stats[bg * 2] = mean;
    stats[bg * 2 + 1] = rsqrtf(var + GN_EPS);
  }
}

// ------- GN apply + transpose: x (b,c,n) f32 -> hT (b,n,c) bf16 ----------
__global__ __launch_bounds__(256) void gn_apply_t(const float* __restrict__ x,
                                                  const float* __restrict__ stats,
                                                  const float* __restrict__ gw,
                                                  const float* __restrict__ gb,
                                                  unsigned short* __restrict__ hT) {
  __shared__ float tile[64][65];
  int b = blockIdx.z, c0 = blockIdx.y * 64, n0 = blockIdx.x * 64;
  int t = threadIdx.x;
  int tc4 = t & 15, tr = t >> 4;
  const float* xb = x + ((size_t)b * CCH + c0) * NPIX + n0;
#pragma unroll
  for (int j = 0; j < 4; ++j) {
    int row = tr + j * 16;
    int c = c0 + row;
    float mean = stats[((size_t)b * NGRP + (c >> 4)) * 2];
    float rstd = stats[((size_t)b * NGRP + (c >> 4)) * 2 + 1];
    float ga = gw[c] * rstd;
    float be = gb[c] - mean * ga;
    f32x4 v = *(const f32x4*)(xb + (size_t)row * NPIX + tc4 * 4);
    tile[row][tc4 * 4 + 0] = v.x * ga + be;
    tile[row][tc4 * 4 + 1] = v.y * ga + be;
    tile[row][tc4 * 4 + 2] = v.z * ga + be;
    tile[row][tc4 * 4 + 3] = v.w * ga + be;
  }
  __syncthreads();
  int cc = t & 7, nr = t >> 3;
  unsigned short* outp = hT + ((size_t)b * NPIX + n0) * CCH + c0;
#pragma unroll
  for (int j = 0; j < 2; ++j) {
    int n = nr + j * 32;
    ushort8 pk;
#pragma unroll
    for (int i = 0; i < 8; ++i) pk[i] = f2bf(tile[cc * 8 + i][n]);
    *(ushort8*)(outp + (size_t)n * CCH + cc * 8) = pk;
  }
}

// ---------------- fp32 -> bf16 weight conversion ----------------
__global__ __launch_bounds__(256) void f32_to_bf16(const float* __restrict__ src,
                                                   unsigned short* __restrict__ dst,
                                                   int n4) {
  int i = blockIdx.x * 256 + threadIdx.x;
  if (i < n4) {
    f32x4 v = ((const f32x4*)src)[i];
    ushort4v o;
    o.x = f2bf(v.x); o.y = f2bf(v.y); o.z = f2bf(v.z); o.w = f2bf(v.w);
    ((ushort4v*)dst)[i] = o;
  }
}

// ---------------- B^T GEMM: C[M,N] = A(M,K) . B(N,K)^T ----------------
// m97-class structure: 128x128 tile, BK=32, 4 waves (2x2), linear LDS,
// global_load_lds width-16 staging, double-buffered, ONE barrier per K-step
// (T3 minimum 2-phase recipe). Prefetch issued BEFORE ds_read+MFMA; the
// compiler drains vmcnt/lgkmcnt at __syncthreads.
// BIAS_MODE: 0 none, 1 bias[row], 2 bias[col]. OUT_BF16: 1 -> ushort out.
// RESID: add resid (fp32) at [row*ldc+col].
template <int BIAS_MODE, int OUT_BF16, int RESID>
__global__ __launch_bounds__(256, 2) void gemm_bt(
    const unsigned short* __restrict__ A, const unsigned short* __restrict__ B,
    void* __restrict__ Cv, const float* __restrict__ bias,
    const float* __restrict__ resid, int M, int N, int K, int lda, int ldb,
    int ldc, long sA, long sB, long sC, long sR, float scale) {
  __shared__ __align__(16) unsigned short lA[2][128 * 32];  // 8 KiB per buf
  __shared__ __align__(16) unsigned short lB[2][128 * 32];
  const int t = threadIdx.x;
  const int lane = t & 63, w = t >> 6;
  const int wr = w >> 1, wc = w & 1;
  const int fr = lane & 15, kg = lane >> 4;
  const int m0 = blockIdx.x * 128, n0 = blockIdx.y * 128;
  const long bz = blockIdx.z;
  const unsigned short* Abz = A + bz * sA;
  const unsigned short* Bbz = B + bz * sB;

  // staging: wave w, chunk j in {0,1}. LDS dest must be (uniform base +
  // lane*16B) [m104]; mapping onto row-major [128][32]:
  //   LDS elem = (w*2+j)*512 + lane*8  ->  row (w*2+j)*16 + lane/4,
  //   col (lane&3)*8. Global src is per-lane (allowed).
  const int srow = w * 32 + (lane >> 2);
  const int scol = (lane & 3) * 8;
  const unsigned short* gA0 = Abz + (size_t)(m0 + srow) * lda + scol;
  const unsigned short* gA1 = Abz + (size_t)(m0 + srow + 16) * lda + scol;
  const unsigned short* gB0 = Bbz + (size_t)(n0 + srow) * ldb + scol;
  const unsigned short* gB1 = Bbz + (size_t)(n0 + srow + 16) * ldb + scol;
  const int lds0 = (w * 2 + 0) * 512 + lane * 8;
  const int lds1 = (w * 2 + 1) * 512 + lane * 8;

#define STAGE(buf, koff)                         \
  do {                                           \
    GLOAD16(gA0 + (koff), &lA[buf][lds0]);       \
    GLOAD16(gA1 + (koff), &lA[buf][lds1]);       \
    GLOAD16(gB0 + (koff), &lB[buf][lds0]);       \
    GLOAD16(gB1 + (koff), &lB[buf][lds1]);       \
  } while (0)

  f32x4 acc[4][4];
  const f32x4 zero = {0.f, 0.f, 0.f, 0.f};
#pragma unroll
  for (int m = 0; m < 4; ++m)
#pragma unroll
    for (int n = 0; n < 4; ++n) acc[m][n] = zero;

  STAGE(0, 0);
  __syncthreads();  // vmcnt(0) drained here by compiler
  int cur = 0;
  const int NT = K >> 5;
  for (int it = 0; it < NT; ++it) {
    if (it + 1 < NT) STAGE(cur ^ 1, (it + 1) * 32);
    short8 af[4], bfr[4];
#pragma unroll
    for (int m = 0; m < 4; ++m)
      af[m] = *(const short8*)&lA[cur][(wr * 64 + m * 16 + fr) * 32 + kg * 8];
#pragma unroll
    for (int n = 0; n < 4; ++n)
      bfr[n] = *(const short8*)&lB[cur][(wc * 64 + n * 16 + fr) * 32 + kg * 8];
#pragma unroll
    for (int m = 0; m < 4; ++m)
#pragma unroll
      for (int n = 0; n < 4; ++n)
        acc[m][n] = __builtin_amdgcn_mfma_f32_16x16x32_bf16(af[m], bfr[n],
                                                            acc[m][n], 0, 0, 0);
    __syncthreads();  // drains vmcnt (next buf ready) + lgkmcnt (cur buf free)
    cur ^= 1;
  }
#undef STAGE

  // epilogue: C/D layout col = lane&15, row = (lane>>4)*4 + reg  [m89]
  const int rowbase = m0 + wr * 64 + kg * 4;
  const int colbase = n0 + wc * 64 + fr;
#pragma unroll
  for (int m = 0; m < 4; ++m) {
#pragma unroll
    for (int n = 0; n < 4; ++n) {
      int col = colbase + n * 16;
#pragma unroll
      for (int r = 0; r < 4; ++r) {
        int row = rowbase + m * 16 + r;
        float v = acc[m][n][r] * scale;
        if (BIAS_MODE == 1) v += bias[row];
        if (BIAS_MODE == 2) v += bias[col];
        if (RESID) v += resid[(size_t)bz * sR + (size_t)row * ldc + col];
        size_t idx = (size_t)bz * sC + (size_t)row * ldc + col;
        if (OUT_BF16)
          ((unsigned short*)Cv)[idx] = f2bf(v);
        else
          ((float*)Cv)[idx] = v;
      }
    }
  }
}

// ---------------- row softmax: S (4096 f32) -> P (4096 bf16) ----------------
__global__ __launch_bounds__(256) void softmax_rows(const float* __restrict__ S,
                                                    unsigned short* __restrict__ P) {
  const int row = blockIdx.x;
  const int t = threadIdx.x;
  const float* Sr = S + (size_t)row * NPIX;
  f32x4 v[4];
  float mx = -3.4e38f;
#pragma unroll
  for (int j = 0; j < 4; ++j) {
    v[j] = *(const f32x4*)(Sr + j * 1024 + t * 4);
    mx = fmaxf(mx, fmaxf(fmaxf(v[j].x, v[j].y), fmaxf(v[j].z, v[j].w)));
  }
  for (int off = 32; off > 0; off >>= 1) mx = fmaxf(mx, __shfl_xor(mx, off, 64));
  __shared__ float r1[4], r2[4];
  int lane = t & 63, wid = t >> 6;
  if (lane == 0) r1[wid] = mx;
  __syncthreads();
  mx = fmaxf(fmaxf(r1[0], r1[1]), fmaxf(r1[2], r1[3]));
  float sum = 0.f;
#pragma unroll
  for (int j = 0; j < 4; ++j) {
    v[j].x = __expf(v[j].x - mx);
    v[j].y = __expf(v[j].y - mx);
    v[j].z = __expf(v[j].z - mx);
    v[j].w = __expf(v[j].w - mx);
    sum += v[j].x + v[j].y + v[j].z + v[j].w;
  }
  for (int off = 32; off > 0; off >>= 1) sum += __shfl_xor(sum, off, 64);
  if (lane == 0) r2[wid] = sum;
  __syncthreads();
  float inv = 1.f / (r2[0] + r2[1] + r2[2] + r2[3]);
  unsigned short* Pr = P + (size_t)row * NPIX;
#pragma unroll
  for (int j = 0; j < 4; ++j) {
    ushort4v o;
    o.x = f2bf(v[j].x * inv);
    o.y = f2bf(v[j].y * inv);
    o.z = f2bf(v[j].z * inv);
    o.w = f2bf(v[j].w * inv);
    *(ushort4v*)(Pr + j * 1024 + t * 4) = o;
  }
}

extern "C" void kernel_launch(void* const* d_in, const int* in_sizes, int n_in,
                              void* d_out, int out_size, void* d_ws, size_t ws_size,
                              hipStream_t stream) {
  const float* x = (const float*)d_in[0];
  const float* gnw = (const float*)d_in[1];
  const float* gnb = (const float*)d_in[2];
  const float* wq = (const float*)d_in[3];
  const float* bq = (const float*)d_in[4];
  const float* wk = (const float*)d_in[5];
  const float* bk = (const float*)d_in[6];
  const float* wv = (const float*)d_in[7];
  const float* bv = (const float*)d_in[8];
  const float* wp = (const float*)d_in[9];
  const float* bp = (const float*)d_in[10];
  float* out = (float*)d_out;

  const size_t BS = (size_t)NPIX * CCH;   // elems per batch-slab
  const size_t PB = (size_t)NPIX * NPIX;  // elems per P batch (bf16)

  char* ws = (char*)d_ws;
  float* stats = (float*)ws;
  unsigned short* hT = (unsigned short*)(ws + 1024);
  unsigned short* Abuf = hT;  // Aout aliases hT (hT dead after v-GEMM)
  unsigned short* qb = hT + BATCH * BS;
  unsigned short* kTb = qb + BATCH * BS;
  unsigned short* vb = kTb + BATCH * BS;
  unsigned short* wqb = vb + BATCH * BS;
  unsigned short* wkb = wqb + CCH * CCH;
  unsigned short* wvb = wkb + CCH * CCH;
  unsigned short* wpb = wvb + CCH * CCH;
  float* Sb = (float*)(wpb + CCH * CCH);  // 64 MiB fp32, reused per batch
  unsigned short* Pb = (unsigned short*)(Sb + PB);
  size_t need2 = (size_t)((char*)(Pb + 2 * PB) - ws);
  size_t need4 = (size_t)((char*)(Pb + 4 * PB) - ws);
  if (ws_size < need2) return;  // distinct failure signal
  const bool p4 = ws_size >= need4;

  f32_to_bf16<<<256, 256, 0, stream>>>(wq, wqb, CCH * CCH / 4);
  f32_to_bf16<<<256, 256, 0, stream>>>(wk, wkb, CCH * CCH / 4);
  f32_to_bf16<<<256, 256, 0, stream>>>(wv, wvb, CCH * CCH / 4);
  f32_to_bf16<<<256, 256, 0, stream>>>(wp, wpb, CCH * CCH / 4);

  gn_stats<<<BATCH * NGRP, 256, 0, stream>>>(x, stats);
  gn_apply_t<<<dim3(NPIX / 64, CCH / 64, BATCH), 256, 0, stream>>>(x, stats, gnw,
                                                                   gnb, hT);

  // q[n,o] = sum_c hT[n,c] wq[o,c] + bq[o]   (bias over col)
  gemm_bt<2, 1, 0><<<dim3(32, 4, BATCH), 256, 0, stream>>>(
      hT, wqb, qb, bq, nullptr, NPIX, CCH, CCH, CCH, CCH, CCH, (long)BS, 0,
      (long)BS, 0, 1.f);
  // kT[m,o] = sum_c hT[m,c] wk[o,c] + bk[o]
  gemm_bt<2, 1, 0><<<dim3(32, 4, BATCH), 256, 0, stream>>>(
      hT, wkb, kTb, bk, nullptr, NPIX, CCH, CCH, CCH, CCH, CCH, (long)BS, 0,
      (long)BS, 0, 1.f);
  // v[c,m] = sum_c' wv[c,c'] hT[m,c'] + bv[c]   (bias over row)
  gemm_bt<1, 1, 0><<<dim3(4, 32, BATCH), 256, 0, stream>>>(
      wvb, hT, vb, bv, nullptr, CCH, NPIX, CCH, CCH, CCH, NPIX, 0, (long)BS,
      (long)BS, 0, 1.f);

  const float sscale = 0.044194173824159216f;  // 512^-0.5
  if (p4) {
    for (int b = 0; b < 4; ++b) {
      // S[q,m] = scale * sum_o q[q,o] kT[m,o]   (fp32)
      gemm_bt<0, 0, 0><<<dim3(32, 32, 1), 256, 0, stream>>>(
          qb + (size_t)b * BS, kTb + (size_t)b * BS, Sb, nullptr, nullptr, NPIX,
          NPIX, CCH, CCH, CCH, NPIX, 0, 0, 0, 0, sscale);
      softmax_rows<<<NPIX, 256, 0, stream>>>(Sb, Pb + (size_t)b * PB);
    }
    // AoutT[q,c] = sum_m P[q,m] v[c,m], all 4 batches (512 blocks, 2/CU)
    gemm_bt<0, 1, 0><<<dim3(32, 4, BATCH), 256, 0, stream>>>(
        Pb, vb, Abuf, nullptr, nullptr, NPIX, CCH, NPIX, NPIX, NPIX, CCH,
        (long)PB, (long)BS, (long)BS, 0, 1.f);
  } else {
    for (int p = 0; p < 2; ++p) {
      for (int i = 0; i < 2; ++i) {
        int b = p * 2 + i;
        gemm_bt<0, 0, 0><<<dim3(32, 32, 1), 256, 0, stream>>>(
            qb + (size_t)b * BS, kTb + (size_t)b * BS, Sb, nullptr, nullptr,
            NPIX, NPIX, CCH, CCH, CCH, NPIX, 0, 0, 0, 0, sscale);
        softmax_rows<<<NPIX, 256, 0, stream>>>(Sb, Pb + (size_t)i * PB);
      }
      gemm_bt<0, 1, 0><<<dim3(32, 4, 2), 256, 0, stream>>>(
          Pb, vb + (size_t)p * 2 * BS, Abuf + (size_t)p * 2 * BS, nullptr,
          nullptr, NPIX, CCH, NPIX, NPIX, NPIX, CCH, (long)PB, (long)BS,
          (long)BS, 0, 1.f);
    }
  }
  // out[o,n] = sum_c wp[o,c] AoutT[n,c] + bp[o] + x[b,o,n]
  gemm_bt<1, 0, 1><<<dim3(4, 32, BATCH), 256, 0, stream>>>(
      wpb, Abuf, out, bp, x, CCH, NPIX, CCH, CCH, CCH, NPIX, 0, (long)BS,
      (long)BS, (long)BS, 1.f);
}

// Round 3
// 355.048 us; speedup vs baseline: 1.2395x; 1.2395x over previous
//
#include <hip/hip_runtime.h>

#define BATCH 4
#define CCH 512
#define NPIX 4096
#define NGRP 32
#define GSZ 16
#define GN_EPS 1e-6f

typedef __attribute__((ext_vector_type(8))) short short8;
typedef __attribute__((ext_vector_type(8))) unsigned short ushort8;
typedef __attribute__((ext_vector_type(4))) unsigned short ushort4v;
typedef __attribute__((ext_vector_type(4))) float f32x4;

__device__ inline unsigned short f2bf(float f) {
  unsigned u = __float_as_uint(f);
  unsigned r = u + 0x7fffu + ((u >> 16) & 1u);
  return (unsigned short)(r >> 16);
}
__device__ inline float bf2f(unsigned short us) {
  return __uint_as_float(((unsigned)us) << 16);
}

// ---------------- GroupNorm stats: one block per (b, group) ----------------
__global__ __launch_bounds__(256) void gn_stats(const float* __restrict__ x,
                                                float* __restrict__ stats) {
  int bg = blockIdx.x;  // b*32 + g ; group data is contiguous 16*4096 floats
  const f32x4* base = (const f32x4*)(x + (size_t)bg * (GSZ * NPIX));
  float s = 0.f, ss = 0.f;
  const int n4 = GSZ * NPIX / 4;  // 16384
  for (int i = threadIdx.x; i < n4; i += 256) {
    f32x4 v = base[i];
    s += v.x + v.y + v.z + v.w;
    ss += v.x * v.x + v.y * v.y + v.z * v.z + v.w * v.w;
  }
  for (int off = 32; off > 0; off >>= 1) {
    s += __shfl_xor(s, off, 64);
    ss += __shfl_xor(ss, off, 64);
  }
  __shared__ float rs[4], rss[4];
  int lane = threadIdx.x & 63, wid = threadIdx.x >> 6;
  if (lane == 0) { rs[wid] = s; rss[wid] = ss; }
  __syncthreads();
  if (threadIdx.x == 0) {
    float S = rs[0] + rs[1] + rs[2] + rs[3];
    float SS = rss[0] + rss[1] + rss[2] + rss[3];
    const float inv = 1.f / (float)(GSZ * NPIX);
    float mean = S * inv;
    float var = SS * inv - mean * mean;
    stats[bg * 2] = mean;
    stats[bg * 2 + 1] = rsqrtf(var + GN_EPS);
  }
}

// ------- GN apply + transpose: x (b,c,n) f32 -> hT (b,n,c) bf16 ----------
__global__ __launch_bounds__(256) void gn_apply_t(const float* __restrict__ x,
                                                  const float* __restrict__ stats,
                                                  const float* __restrict__ gw,
                                                  const float* __restrict__ gb,
                                                  unsigned short* __restrict__ hT) {
  __shared__ float tile[64][65];
  int b = blockIdx.z, c0 = blockIdx.y * 64, n0 = blockIdx.x * 64;
  int t = threadIdx.x;
  int tc4 = t & 15, tr = t >> 4;
  const float* xb = x + ((size_t)b * CCH + c0) * NPIX + n0;
#pragma unroll
  for (int j = 0; j < 4; ++j) {
    int row = tr + j * 16;
    int c = c0 + row;
    float mean = stats[((size_t)b * NGRP + (c >> 4)) * 2];
    float rstd = stats[((size_t)b * NGRP + (c >> 4)) * 2 + 1];
    float ga = gw[c] * rstd;
    float be = gb[c] - mean * ga;
    f32x4 v = *(const f32x4*)(xb + (size_t)row * NPIX + tc4 * 4);
    tile[row][tc4 * 4 + 0] = v.x * ga + be;
    tile[row][tc4 * 4 + 1] = v.y * ga + be;
    tile[row][tc4 * 4 + 2] = v.z * ga + be;
    tile[row][tc4 * 4 + 3] = v.w * ga + be;
  }
  __syncthreads();
  int cc = t & 7, nr = t >> 3;
  unsigned short* outp = hT + ((size_t)b * NPIX + n0) * CCH + c0;
#pragma unroll
  for (int j = 0; j < 2; ++j) {
    int n = nr + j * 32;
    ushort8 pk;
#pragma unroll
    for (int i = 0; i < 8; ++i) pk[i] = f2bf(tile[cc * 8 + i][n]);
    *(ushort8*)(outp + (size_t)n * CCH + cc * 8) = pk;
  }
}

// ---------------- fp32 -> bf16 weight conversion ----------------
__global__ __launch_bounds__(256) void f32_to_bf16(const float* __restrict__ src,
                                                   unsigned short* __restrict__ dst,
                                                   int n4) {
  int i = blockIdx.x * 256 + threadIdx.x;
  if (i < n4) {
    f32x4 v = ((const f32x4*)src)[i];
    ushort4v o;
    o.x = f2bf(v.x); o.y = f2bf(v.y); o.z = f2bf(v.z); o.w = f2bf(v.w);
    ((ushort4v*)dst)[i] = o;
  }
}

// ---------------- B^T GEMM: C[M,N] = A(M,K) . B(N,K)^T ----------------
// 128x128 tile, BK=32, 4 waves (2x2). Reg-staged, TWO tiles in flight
// (loads issued 2 compute-phases before their ds_write -> ~1000cyc slack
// against L2-miss latency). Single-buffered padded LDS (20KB).
// SWZ: XCD-chunked block swizzle (all grids have nwg%8==0 -> bijective).
//   0: chunked, x-fastest decode (bx=m-tile)
//   1: 32x32 grid, per-XCD 16(m)x8(n) patch (S-GEMM; 3.1MB/XCD < 4MB L2)
//   2: chunked, x-fastest decode with x=n-tile, y=m-tile (A-panel sharers
//      consecutive -> same XCD)
// BIAS_MODE: 0 none, 1 bias[row], 2 bias[col]. OUT_BF16: 1 -> ushort out.
// RESID: add resid (fp32) at [row*ldc+col].
template <int BIAS_MODE, int OUT_BF16, int RESID, int SWZ>
__global__ __launch_bounds__(256, 2) void gemm_bt(
    const unsigned short* __restrict__ A, const unsigned short* __restrict__ B,
    void* __restrict__ Cv, const float* __restrict__ bias,
    const float* __restrict__ resid, int M, int N, int K, int lda, int ldb,
    int ldc, long sA, long sB, long sC, long sR, float scale) {
  __shared__ __align__(16) unsigned short lA[128][40];  // 32 data + 8 pad
  __shared__ __align__(16) unsigned short lB[128][40];
  const int t = threadIdx.x;
  const int lane = t & 63, w = t >> 6;
  const int wr = w >> 1, wc = w & 1;
  const int fr = lane & 15, kg = lane >> 4;

  // ---- XCD-chunked swizzle ----
  unsigned orig = blockIdx.x + gridDim.x * (blockIdx.y + gridDim.y * blockIdx.z);
  unsigned nwg = gridDim.x * gridDim.y * gridDim.z;
  unsigned tid = (orig & 7) * (nwg >> 3) + (orig >> 3);
  int mt, ntl, bz;
  if (SWZ == 1) {
    unsigned u = tid & 15, v = (tid >> 4) & 7, p = tid >> 7;
    mt = (int)((p & 1) * 16 + u);
    ntl = (int)((p >> 1) * 8 + v);
    bz = 0;
  } else if (SWZ == 2) {
    unsigned bx = tid % gridDim.x, r = tid / gridDim.x;
    ntl = (int)bx;
    mt = (int)(r % gridDim.y);
    bz = (int)(r / gridDim.y);
  } else {
    unsigned bx = tid % gridDim.x, r = tid / gridDim.x;
    mt = (int)bx;
    ntl = (int)(r % gridDim.y);
    bz = (int)(r / gridDim.y);
  }
  const int m0 = mt * 128, n0 = ntl * 128;

  const unsigned short* Abz = A + (long)bz * sA;
  const unsigned short* Bbz = B + (long)bz * sB;
  const int srow = t >> 1, skc = (t & 1) * 16;
  const unsigned short* gA = Abz + (size_t)(m0 + srow) * lda + skc;
  const unsigned short* gB = Bbz + (size_t)(n0 + srow) * ldb + skc;

  // prologue: tiles 0 (set X) and 1 (set Y) in flight. NT is always even
  // (K=512 or 4096) and >= 2.
  short8 a0X = *(const short8*)(gA);
  short8 a1X = *(const short8*)(gA + 8);
  short8 b0X = *(const short8*)(gB);
  short8 b1X = *(const short8*)(gB + 8);
  short8 a0Y = *(const short8*)(gA + 32);
  short8 a1Y = *(const short8*)(gA + 40);
  short8 b0Y = *(const short8*)(gB + 32);
  short8 b1Y = *(const short8*)(gB + 40);

  f32x4 acc[4][4];
  const f32x4 zero = {0.f, 0.f, 0.f, 0.f};
#pragma unroll
  for (int m = 0; m < 4; ++m)
#pragma unroll
    for (int n = 0; n < 4; ++n) acc[m][n] = zero;

  const int NT = K >> 5;
#define COMPUTE()                                                             \
  do {                                                                        \
    short8 af[4], bfr[4];                                                     \
    _Pragma("unroll") for (int m = 0; m < 4; ++m) af[m] =                     \
        *(const short8*)&lA[wr * 64 + m * 16 + fr][kg * 8];                   \
    _Pragma("unroll") for (int n = 0; n < 4; ++n) bfr[n] =                    \
        *(const short8*)&lB[wc * 64 + n * 16 + fr][kg * 8];                   \
    _Pragma("unroll") for (int m = 0; m < 4; ++m)                             \
        _Pragma("unroll") for (int n = 0; n < 4; ++n) acc[m][n] =             \
            __builtin_amdgcn_mfma_f32_16x16x32_bf16(af[m], bfr[n],            \
                                                    acc[m][n], 0, 0, 0);      \
  } while (0)

  for (int it = 0; it < NT; it += 2) {
    // even phase: tile it (set X)
    __syncthreads();
    *(short8*)&lA[srow][skc] = a0X;
    *(short8*)&lA[srow][skc + 8] = a1X;
    *(short8*)&lB[srow][skc] = b0X;
    *(short8*)&lB[srow][skc + 8] = b1X;
    if (it + 2 < NT) {
      a0X = *(const short8*)(gA + (it + 2) * 32);
      a1X = *(const short8*)(gA + (it + 2) * 32 + 8);
      b0X = *(const short8*)(gB + (it + 2) * 32);
      b1X = *(const short8*)(gB + (it + 2) * 32 + 8);
    }
    __syncthreads();
    COMPUTE();
    // odd phase: tile it+1 (set Y)
    __syncthreads();
    *(short8*)&lA[srow][skc] = a0Y;
    *(short8*)&lA[srow][skc + 8] = a1Y;
    *(short8*)&lB[srow][skc] = b0Y;
    *(short8*)&lB[srow][skc + 8] = b1Y;
    if (it + 3 < NT) {
      a0Y = *(const short8*)(gA + (it + 3) * 32);
      a1Y = *(const short8*)(gA + (it + 3) * 32 + 8);
      b0Y = *(const short8*)(gB + (it + 3) * 32);
      b1Y = *(const short8*)(gB + (it + 3) * 32 + 8);
    }
    __syncthreads();
    COMPUTE();
  }
#undef COMPUTE

  // epilogue: C/D layout col = lane&15, row = (lane>>4)*4 + reg  [m89]
  const int rowbase = m0 + wr * 64 + kg * 4;
  const int colbase = n0 + wc * 64 + fr;
#pragma unroll
  for (int m = 0; m < 4; ++m) {
#pragma unroll
    for (int n = 0; n < 4; ++n) {
      int col = colbase + n * 16;
#pragma unroll
      for (int r = 0; r < 4; ++r) {
        int row = rowbase + m * 16 + r;
        float v = acc[m][n][r] * scale;
        if (BIAS_MODE == 1) v += bias[row];
        if (BIAS_MODE == 2) v += bias[col];
        if (RESID) v += resid[(size_t)bz * sR + (size_t)row * ldc + col];
        size_t idx = (size_t)bz * sC + (size_t)row * ldc + col;
        if (OUT_BF16)
          ((unsigned short*)Cv)[idx] = f2bf(v);
        else
          ((float*)Cv)[idx] = v;
      }
    }
  }
}

// --------- row softmax: S (4096 bf16) -> P (4096 bf16) ----------
__global__ __launch_bounds__(256) void softmax_rows(
    const unsigned short* __restrict__ S, unsigned short* __restrict__ P) {
  const int row = blockIdx.x;
  const int t = threadIdx.x;
  const unsigned short* Sr = S + (size_t)row * NPIX;
  float f[16];
  float mx = -3.4e38f;
#pragma unroll
  for (int j = 0; j < 2; ++j) {
    ushort8 u = *(const ushort8*)(Sr + j * 2048 + t * 8);
#pragma unroll
    for (int i = 0; i < 8; ++i) {
      f[j * 8 + i] = bf2f(u[i]);
      mx = fmaxf(mx, f[j * 8 + i]);
    }
  }
  for (int off = 32; off > 0; off >>= 1) mx = fmaxf(mx, __shfl_xor(mx, off, 64));
  __shared__ float r1[4], r2[4];
  int lane = t & 63, wid = t >> 6;
  if (lane == 0) r1[wid] = mx;
  __syncthreads();
  mx = fmaxf(fmaxf(r1[0], r1[1]), fmaxf(r1[2], r1[3]));
  float sum = 0.f;
#pragma unroll
  for (int i = 0; i < 16; ++i) {
    f[i] = __expf(f[i] - mx);
    sum += f[i];
  }
  for (int off = 32; off > 0; off >>= 1) sum += __shfl_xor(sum, off, 64);
  if (lane == 0) r2[wid] = sum;
  __syncthreads();
  float inv = 1.f / (r2[0] + r2[1] + r2[2] + r2[3]);
  unsigned short* Pr = P + (size_t)row * NPIX;
#pragma unroll
  for (int j = 0; j < 2; ++j) {
    ushort8 o;
#pragma unroll
    for (int i = 0; i < 8; ++i) o[i] = f2bf(f[j * 8 + i] * inv);
    *(ushort8*)(Pr + j * 2048 + t * 8) = o;
  }
}

extern "C" void kernel_launch(void* const* d_in, const int* in_sizes, int n_in,
                              void* d_out, int out_size, void* d_ws, size_t ws_size,
                              hipStream_t stream) {
  const float* x = (const float*)d_in[0];
  const float* gnw = (const float*)d_in[1];
  const float* gnb = (const float*)d_in[2];
  const float* wq = (const float*)d_in[3];
  const float* bq = (const float*)d_in[4];
  const float* wk = (const float*)d_in[5];
  const float* bk = (const float*)d_in[6];
  const float* wv = (const float*)d_in[7];
  const float* bv = (const float*)d_in[8];
  const float* wp = (const float*)d_in[9];
  const float* bp = (const float*)d_in[10];
  float* out = (float*)d_out;

  const size_t BS = (size_t)NPIX * CCH;   // elems per batch-slab
  const size_t PB = (size_t)NPIX * NPIX;  // elems per S/P batch (bf16)

  char* ws = (char*)d_ws;
  float* stats = (float*)ws;
  unsigned short* hT = (unsigned short*)(ws + 1024);
  unsigned short* Abuf = hT;  // Aout aliases hT (hT dead after v-GEMM)
  unsigned short* qb = hT + BATCH * BS;
  unsigned short* kTb = qb + BATCH * BS;
  unsigned short* vb = kTb + BATCH * BS;
  unsigned short* wqb = vb + BATCH * BS;
  unsigned short* wkb = wqb + CCH * CCH;
  unsigned short* wvb = wkb + CCH * CCH;
  unsigned short* wpb = wvb + CCH * CCH;
  unsigned short* Sb = wpb + CCH * CCH;  // 32 MiB bf16, reused per batch
  unsigned short* Pb = Sb + PB;
  size_t need2 = (size_t)((char*)(Pb + 2 * PB) - ws);
  size_t need4 = (size_t)((char*)(Pb + 4 * PB) - ws);
  if (ws_size < need2) return;  // distinct failure signal
  const bool p4 = ws_size >= need4;

  f32_to_bf16<<<256, 256, 0, stream>>>(wq, wqb, CCH * CCH / 4);
  f32_to_bf16<<<256, 256, 0, stream>>>(wk, wkb, CCH * CCH / 4);
  f32_to_bf16<<<256, 256, 0, stream>>>(wv, wvb, CCH * CCH / 4);
  f32_to_bf16<<<256, 256, 0, stream>>>(wp, wpb, CCH * CCH / 4);

  gn_stats<<<BATCH * NGRP, 256, 0, stream>>>(x, stats);
  gn_apply_t<<<dim3(NPIX / 64, CCH / 64, BATCH), 256, 0, stream>>>(x, stats, gnw,
                                                                   gnb, hT);

  // q[n,o] = sum_c hT[n,c] wq[o,c] + bq[o]  (SWZ=2: grid x = n-tiles)
  gemm_bt<2, 1, 0, 2><<<dim3(4, 32, BATCH), 256, 0, stream>>>(
      hT, wqb, qb, bq, nullptr, NPIX, CCH, CCH, CCH, CCH, CCH, (long)BS, 0,
      (long)BS, 0, 1.f);
  // kT[m,o] = sum_c hT[m,c] wk[o,c] + bk[o]
  gemm_bt<2, 1, 0, 2><<<dim3(4, 32, BATCH), 256, 0, stream>>>(
      hT, wkb, kTb, bk, nullptr, NPIX, CCH, CCH, CCH, CCH, CCH, (long)BS, 0,
      (long)BS, 0, 1.f);
  // v[c,m] = sum_c' wv[c,c'] hT[m,c'] + bv[c]
  gemm_bt<1, 1, 0, 0><<<dim3(4, 32, BATCH), 256, 0, stream>>>(
      wvb, hT, vb, bv, nullptr, CCH, NPIX, CCH, CCH, CCH, NPIX, 0, (long)BS,
      (long)BS, 0, 1.f);

  const float sscale = 0.044194173824159216f;  // 512^-0.5
  if (p4) {
    for (int b = 0; b < 4; ++b) {
      // S[q,m] = scale * sum_o q[q,o] kT[m,o]  (bf16 out; SWZ=1 patch)
      gemm_bt<0, 1, 0, 1><<<dim3(32, 32, 1), 256, 0, stream>>>(
          qb + (size_t)b * BS, kTb + (size_t)b * BS, Sb, nullptr, nullptr, NPIX,
          NPIX, CCH, CCH, CCH, NPIX, 0, 0, 0, 0, sscale);
      softmax_rows<<<NPIX, 256, 0, stream>>>(Sb, Pb + (size_t)b * PB);
    }
    // AoutT[q,c] = sum_m P[q,m] v[c,m], all 4 batches
    gemm_bt<0, 1, 0, 2><<<dim3(4, 32, BATCH), 256, 0, stream>>>(
        Pb, vb, Abuf, nullptr, nullptr, NPIX, CCH, NPIX, NPIX, NPIX, CCH,
        (long)PB, (long)BS, (long)BS, 0, 1.f);
  } else {
    for (int p = 0; p < 2; ++p) {
      for (int i = 0; i < 2; ++i) {
        int b = p * 2 + i;
        gemm_bt<0, 1, 0, 1><<<dim3(32, 32, 1), 256, 0, stream>>>(
            qb + (size_t)b * BS, kTb + (size_t)b * BS, Sb, nullptr, nullptr,
            NPIX, NPIX, CCH, CCH, CCH, NPIX, 0, 0, 0, 0, sscale);
        softmax_rows<<<NPIX, 256, 0, stream>>>(Sb, Pb + (size_t)i * PB);
      }
      gemm_bt<0, 1, 0, 2><<<dim3(4, 32, 2), 256, 0, stream>>>(
          Pb, vb + (size_t)p * 2 * BS, Abuf + (size_t)p * 2 * BS, nullptr,
          nullptr, NPIX, CCH, NPIX, NPIX, NPIX, CCH, (long)PB, (long)BS,
          (long)BS, 0, 1.f);
    }
  }
  // out[o,n] = sum_c wp[o,c] AoutT[n,c] + bp[o] + x[b,o,n]
  gemm_bt<1, 0, 1, 0><<<dim3(4, 32, BATCH), 256, 0, stream>>>(
      wpb, Abuf, out, bp, x, CCH, NPIX, CCH, CCH, CCH, NPIX, 0, (long)BS,
      (long)BS, (long)BS, 1.f);
}

// Round 4
// 340.522 us; speedup vs baseline: 1.2924x; 1.0427x over previous
//
#include <hip/hip_runtime.h>

#define BATCH 4
#define CCH 512
#define NPIX 4096
#define NGRP 32
#define GSZ 16
#define GN_EPS 1e-6f

typedef __attribute__((ext_vector_type(8))) short short8;
typedef __attribute__((ext_vector_type(8))) unsigned short ushort8;
typedef __attribute__((ext_vector_type(4))) unsigned short ushort4v;
typedef __attribute__((ext_vector_type(4))) float f32x4;

__device__ inline unsigned short f2bf(float f) {
  unsigned u = __float_as_uint(f);
  unsigned r = u + 0x7fffu + ((u >> 16) & 1u);
  return (unsigned short)(r >> 16);
}
__device__ inline float bf2f(unsigned short us) {
  return __uint_as_float(((unsigned)us) << 16);
}

// ---------------- GroupNorm stats: one block per (b, group) ----------------
__global__ __launch_bounds__(256) void gn_stats(const float* __restrict__ x,
                                                float* __restrict__ stats) {
  int bg = blockIdx.x;
  const f32x4* base = (const f32x4*)(x + (size_t)bg * (GSZ * NPIX));
  float s = 0.f, ss = 0.f;
  const int n4 = GSZ * NPIX / 4;
  for (int i = threadIdx.x; i < n4; i += 256) {
    f32x4 v = base[i];
    s += v.x + v.y + v.z + v.w;
    ss += v.x * v.x + v.y * v.y + v.z * v.z + v.w * v.w;
  }
  for (int off = 32; off > 0; off >>= 1) {
    s += __shfl_xor(s, off, 64);
    ss += __shfl_xor(ss, off, 64);
  }
  __shared__ float rs[4], rss[4];
  int lane = threadIdx.x & 63, wid = threadIdx.x >> 6;
  if (lane == 0) { rs[wid] = s; rss[wid] = ss; }
  __syncthreads();
  if (threadIdx.x == 0) {
    float S = rs[0] + rs[1] + rs[2] + rs[3];
    float SS = rss[0] + rss[1] + rss[2] + rss[3];
    const float inv = 1.f / (float)(GSZ * NPIX);
    float mean = S * inv;
    float var = SS * inv - mean * mean;
    stats[bg * 2] = mean;
    stats[bg * 2 + 1] = rsqrtf(var + GN_EPS);
  }
}

// ------- GN apply + transpose: x (b,c,n) f32 -> hT (b,n,c) bf16 ----------
__global__ __launch_bounds__(256) void gn_apply_t(const float* __restrict__ x,
                                                  const float* __restrict__ stats,
                                                  const float* __restrict__ gw,
                                                  const float* __restrict__ gb,
                                                  unsigned short* __restrict__ hT) {
  __shared__ float tile[64][65];
  int b = blockIdx.z, c0 = blockIdx.y * 64, n0 = blockIdx.x * 64;
  int t = threadIdx.x;
  int tc4 = t & 15, tr = t >> 4;
  const float* xb = x + ((size_t)b * CCH + c0) * NPIX + n0;
#pragma unroll
  for (int j = 0; j < 4; ++j) {
    int row = tr + j * 16;
    int c = c0 + row;
    float mean = stats[((size_t)b * NGRP + (c >> 4)) * 2];
    float rstd = stats[((size_t)b * NGRP + (c >> 4)) * 2 + 1];
    float ga = gw[c] * rstd;
    float be = gb[c] - mean * ga;
    f32x4 v = *(const f32x4*)(xb + (size_t)row * NPIX + tc4 * 4);
    tile[row][tc4 * 4 + 0] = v.x * ga + be;
    tile[row][tc4 * 4 + 1] = v.y * ga + be;
    tile[row][tc4 * 4 + 2] = v.z * ga + be;
    tile[row][tc4 * 4 + 3] = v.w * ga + be;
  }
  __syncthreads();
  int cc = t & 7, nr = t >> 3;
  unsigned short* outp = hT + ((size_t)b * NPIX + n0) * CCH + c0;
#pragma unroll
  for (int j = 0; j < 2; ++j) {
    int n = nr + j * 32;
    ushort8 pk;
#pragma unroll
    for (int i = 0; i < 8; ++i) pk[i] = f2bf(tile[cc * 8 + i][n]);
    *(ushort8*)(outp + (size_t)n * CCH + cc * 8) = pk;
  }
}

// ---------------- fp32 -> bf16 weight conversion ----------------
__global__ __launch_bounds__(256) void f32_to_bf16(const float* __restrict__ src,
                                                   unsigned short* __restrict__ dst,
                                                   int n4) {
  int i = blockIdx.x * 256 + threadIdx.x;
  if (i < n4) {
    f32x4 v = ((const f32x4*)src)[i];
    ushort4v o;
    o.x = f2bf(v.x); o.y = f2bf(v.y); o.z = f2bf(v.z); o.w = f2bf(v.w);
    ((ushort4v*)dst)[i] = o;
  }
}

// ---------------- B^T GEMM (unchanged from round 3, SWZ 0/2 only) --------
template <int BIAS_MODE, int OUT_BF16, int RESID, int SWZ>
__global__ __launch_bounds__(256, 2) void gemm_bt(
    const unsigned short* __restrict__ A, const unsigned short* __restrict__ B,
    void* __restrict__ Cv, const float* __restrict__ bias,
    const float* __restrict__ resid, int M, int N, int K, int lda, int ldb,
    int ldc, long sA, long sB, long sC, long sR, float scale) {
  __shared__ __align__(16) unsigned short lA[128][40];
  __shared__ __align__(16) unsigned short lB[128][40];
  const int t = threadIdx.x;
  const int lane = t & 63, w = t >> 6;
  const int wr = w >> 1, wc = w & 1;
  const int fr = lane & 15, kg = lane >> 4;

  unsigned orig = blockIdx.x + gridDim.x * (blockIdx.y + gridDim.y * blockIdx.z);
  unsigned nwg = gridDim.x * gridDim.y * gridDim.z;
  unsigned tid = (orig & 7) * (nwg >> 3) + (orig >> 3);
  int mt, ntl, bz;
  if (SWZ == 2) {
    unsigned bx = tid % gridDim.x, r = tid / gridDim.x;
    ntl = (int)bx;
    mt = (int)(r % gridDim.y);
    bz = (int)(r / gridDim.y);
  } else {
    unsigned bx = tid % gridDim.x, r = tid / gridDim.x;
    mt = (int)bx;
    ntl = (int)(r % gridDim.y);
    bz = (int)(r / gridDim.y);
  }
  const int m0 = mt * 128, n0 = ntl * 128;

  const unsigned short* Abz = A + (long)bz * sA;
  const unsigned short* Bbz = B + (long)bz * sB;
  const int srow = t >> 1, skc = (t & 1) * 16;
  const unsigned short* gA = Abz + (size_t)(m0 + srow) * lda + skc;
  const unsigned short* gB = Bbz + (size_t)(n0 + srow) * ldb + skc;

  short8 a0X = *(const short8*)(gA);
  short8 a1X = *(const short8*)(gA + 8);
  short8 b0X = *(const short8*)(gB);
  short8 b1X = *(const short8*)(gB + 8);
  short8 a0Y = *(const short8*)(gA + 32);
  short8 a1Y = *(const short8*)(gA + 40);
  short8 b0Y = *(const short8*)(gB + 32);
  short8 b1Y = *(const short8*)(gB + 40);

  f32x4 acc[4][4];
  const f32x4 zero = {0.f, 0.f, 0.f, 0.f};
#pragma unroll
  for (int m = 0; m < 4; ++m)
#pragma unroll
    for (int n = 0; n < 4; ++n) acc[m][n] = zero;

  const int NT = K >> 5;
#define COMPUTE()                                                             \
  do {                                                                        \
    short8 af[4], bfr[4];                                                     \
    _Pragma("unroll") for (int m = 0; m < 4; ++m) af[m] =                     \
        *(const short8*)&lA[wr * 64 + m * 16 + fr][kg * 8];                   \
    _Pragma("unroll") for (int n = 0; n < 4; ++n) bfr[n] =                    \
        *(const short8*)&lB[wc * 64 + n * 16 + fr][kg * 8];                   \
    _Pragma("unroll") for (int m = 0; m < 4; ++m)                             \
        _Pragma("unroll") for (int n = 0; n < 4; ++n) acc[m][n] =             \
            __builtin_amdgcn_mfma_f32_16x16x32_bf16(af[m], bfr[n],            \
                                                    acc[m][n], 0, 0, 0);      \
  } while (0)

  for (int it = 0; it < NT; it += 2) {
    __syncthreads();
    *(short8*)&lA[srow][skc] = a0X;
    *(short8*)&lA[srow][skc + 8] = a1X;
    *(short8*)&lB[srow][skc] = b0X;
    *(short8*)&lB[srow][skc + 8] = b1X;
    if (it + 2 < NT) {
      a0X = *(const short8*)(gA + (it + 2) * 32);
      a1X = *(const short8*)(gA + (it + 2) * 32 + 8);
      b0X = *(const short8*)(gB + (it + 2) * 32);
      b1X = *(const short8*)(gB + (it + 2) * 32 + 8);
    }
    __syncthreads();
    COMPUTE();
    __syncthreads();
    *(short8*)&lA[srow][skc] = a0Y;
    *(short8*)&lA[srow][skc + 8] = a1Y;
    *(short8*)&lB[srow][skc] = b0Y;
    *(short8*)&lB[srow][skc + 8] = b1Y;
    if (it + 3 < NT) {
      a0Y = *(const short8*)(gA + (it + 3) * 32);
      a1Y = *(const short8*)(gA + (it + 3) * 32 + 8);
      b0Y = *(const short8*)(gB + (it + 3) * 32);
      b1Y = *(const short8*)(gB + (it + 3) * 32 + 8);
    }
    __syncthreads();
    COMPUTE();
  }
#undef COMPUTE

  const int rowbase = m0 + wr * 64 + kg * 4;
  const int colbase = n0 + wc * 64 + fr;
#pragma unroll
  for (int m = 0; m < 4; ++m) {
#pragma unroll
    for (int n = 0; n < 4; ++n) {
      int col = colbase + n * 16;
#pragma unroll
      for (int r = 0; r < 4; ++r) {
        int row = rowbase + m * 16 + r;
        float v = acc[m][n][r] * scale;
        if (BIAS_MODE == 1) v += bias[row];
        if (BIAS_MODE == 2) v += bias[col];
        if (RESID) v += resid[(size_t)bz * sR + (size_t)row * ldc + col];
        size_t idx = (size_t)bz * sC + (size_t)row * ldc + col;
        if (OUT_BF16)
          ((unsigned short*)Cv)[idx] = f2bf(v);
        else
          ((float*)Cv)[idx] = v;
      }
    }
  }
}

// =============== fused attention: S = qk^T, P = exp(S*sc), O = P.V^T/l ===
// Block: 64 q-rows, 512 threads (8 waves = 2q x 4c). 256 blocks (1/CU).
// Q in LDS [64][520]; K chunks [128m][136c] / V chunks [512c][32m xor-slot]
// double-buffered in Ks[2]; P roundtrip via Ps [64][136]. No max-subtraction
// (S ~ N(0,1): |S| << fp32 exp range). One barrier per phase (dbuf-safe).
__global__ __launch_bounds__(512, 2) void attn_fused(
    const unsigned short* __restrict__ qg, const unsigned short* __restrict__ kg2,
    const unsigned short* __restrict__ vg, unsigned short* __restrict__ og,
    float scale) {
  __shared__ __align__(16) unsigned short Qs[64 * 520];   // 66560 B
  __shared__ __align__(16) unsigned short Ks[2][17408];   // 2x34816 B
  __shared__ __align__(16) unsigned short Ps[64 * 136];   // 17408 B
  __shared__ float lred[2][32][4];
  __shared__ float linv[64];

  const int t = threadIdx.x;
  const int lane = t & 63;
  const int wid = t >> 6;
  const int wq = wid >> 2, wc = wid & 3;
  const int fr = lane & 15, kgp = lane >> 4;

  unsigned logical = ((unsigned)blockIdx.x & 7) * 32 + ((unsigned)blockIdx.x >> 3);
  const int bz = (int)(logical >> 6), qt = (int)(logical & 63);
  const size_t BS = (size_t)NPIX * CCH;
  const unsigned short* qb = qg + (size_t)bz * BS + (size_t)qt * 64 * CCH;
  const unsigned short* kb = kg2 + (size_t)bz * BS;
  const unsigned short* vb = vg + (size_t)bz * BS;

  // Q -> LDS (synced by first phase barrier)
  {
    const int row = t >> 3, c0 = (t & 7) * 64;
    const unsigned short* src = qb + (size_t)row * CCH + c0;
#pragma unroll
    for (int i = 0; i < 8; ++i)
      *(short8*)&Qs[row * 520 + c0 + i * 8] = *(const short8*)(src + i * 8);
  }

  const int krow = t >> 2, kseg = t & 3;
  const unsigned short* gK = kb + (size_t)krow * CCH + kseg * 32;
  const int kldsoff = krow * 136 + kseg * 32;
  const unsigned short* gV = vb + (size_t)t * NPIX;
  const int vldsbase = t * 32;
  const int vxor = t & 3;

  short8 R0, R1, R2, R3;
#define LOADK(mt_, cc_)                                                       \
  do { const unsigned short* g = gK + (size_t)(mt_) * (128 * CCH) + (cc_) * 128; \
    R0 = *(const short8*)(g); R1 = *(const short8*)(g + 8);                   \
    R2 = *(const short8*)(g + 16); R3 = *(const short8*)(g + 24); } while (0)
#define LOADV(mt_, vc_)                                                       \
  do { const unsigned short* g = gV + (mt_) * 128 + (vc_) * 32;               \
    R0 = *(const short8*)(g); R1 = *(const short8*)(g + 8);                   \
    R2 = *(const short8*)(g + 16); R3 = *(const short8*)(g + 24); } while (0)
#define WRITEK(buf_)                                                          \
  do { unsigned short* d = &Ks[buf_][kldsoff];                                \
    *(short8*)(d) = R0; *(short8*)(d + 8) = R1;                               \
    *(short8*)(d + 16) = R2; *(short8*)(d + 24) = R3; } while (0)
#define WRITEV(buf_)                                                          \
  do { unsigned short* d = &Ks[buf_][vldsbase];                               \
    *(short8*)(d + ((0 ^ vxor) * 8)) = R0; *(short8*)(d + ((1 ^ vxor) * 8)) = R1; \
    *(short8*)(d + ((2 ^ vxor) * 8)) = R2; *(short8*)(d + ((3 ^ vxor) * 8)) = R3; } while (0)

  f32x4 oa[2][8];
  const f32x4 zero = {0.f, 0.f, 0.f, 0.f};
#pragma unroll
  for (int i = 0; i < 2; ++i)
#pragma unroll
    for (int j = 0; j < 8; ++j) oa[i][j] = zero;
  f32x4 racc0 = zero, racc1 = zero;

  LOADK(0, 0);
  for (int mt = 0; mt < 32; ++mt) {
    f32x4 s00 = zero, s01 = zero, s10 = zero, s11 = zero;
#pragma unroll
    for (int ph = 0; ph < 8; ++ph) {
      const int buf = ph & 1;
      // stage current phase's chunk (written while others may still compute
      // phase ph-1 from the other buffer -- race-free by dbuf argument)
      if (ph < 4) WRITEK(buf); else WRITEV(buf);
      // issue next phase's loads (vmcnt slack = one full compute phase)
      if (ph < 3) { LOADK(mt, ph + 1); }
      else if (ph == 3) { LOADV(mt, 0); }
      else if (ph < 7) { LOADV(mt, ph - 3); }
      else { if (mt + 1 < 32) LOADK(mt + 1, 0); }
      __syncthreads();
      if (ph < 4) {
        // S-chunk: c in [ph*128, ph*128+128)
#pragma unroll
        for (int kk = 0; kk < 4; ++kk) {
          short8 a0 = *(const short8*)&Qs[(wq * 32 + fr) * 520 + ph * 128 + kk * 32 + kgp * 8];
          short8 a1 = *(const short8*)&Qs[(wq * 32 + 16 + fr) * 520 + ph * 128 + kk * 32 + kgp * 8];
          short8 b0 = *(const short8*)&Ks[buf][(wc * 32 + fr) * 136 + kk * 32 + kgp * 8];
          short8 b1 = *(const short8*)&Ks[buf][(wc * 32 + 16 + fr) * 136 + kk * 32 + kgp * 8];
          s00 = __builtin_amdgcn_mfma_f32_16x16x32_bf16(a0, b0, s00, 0, 0, 0);
          s01 = __builtin_amdgcn_mfma_f32_16x16x32_bf16(a0, b1, s01, 0, 0, 0);
          s10 = __builtin_amdgcn_mfma_f32_16x16x32_bf16(a1, b0, s10, 0, 0, 0);
          s11 = __builtin_amdgcn_mfma_f32_16x16x32_bf16(a1, b1, s11, 0, 0, 0);
        }
        if (ph == 3) {
          // P = exp(S*scale); rowsums -> racc; P -> Ps (C/D layout [m89]:
          // col=fr (m), row=kgp*4+r (q))
          f32x4 p00, p01, p10, p11;
#pragma unroll
          for (int r = 0; r < 4; ++r) {
            p00[r] = __expf(s00[r] * scale);
            p01[r] = __expf(s01[r] * scale);
            p10[r] = __expf(s10[r] * scale);
            p11[r] = __expf(s11[r] * scale);
          }
          f32x4 rs0 = p00 + p01, rs1 = p10 + p11;
#pragma unroll
          for (int off = 1; off <= 8; off <<= 1) {
#pragma unroll
            for (int r = 0; r < 4; ++r) {
              rs0[r] += __shfl_xor(rs0[r], off, 64);
              rs1[r] += __shfl_xor(rs1[r], off, 64);
            }
          }
          racc0 += rs0;
          racc1 += rs1;
#pragma unroll
          for (int r = 0; r < 4; ++r) {
            Ps[(wq * 32 + kgp * 4 + r) * 136 + wc * 32 + fr] = f2bf(p00[r]);
            Ps[(wq * 32 + kgp * 4 + r) * 136 + wc * 32 + 16 + fr] = f2bf(p01[r]);
            Ps[(wq * 32 + 16 + kgp * 4 + r) * 136 + wc * 32 + fr] = f2bf(p10[r]);
            Ps[(wq * 32 + 16 + kgp * 4 + r) * 136 + wc * 32 + 16 + fr] = f2bf(p11[r]);
          }
        }
      } else {
        const int vc = ph - 4;
        short8 pa0 = *(const short8*)&Ps[(wq * 32 + fr) * 136 + vc * 32 + kgp * 8];
        short8 pa1 = *(const short8*)&Ps[(wq * 32 + 16 + fr) * 136 + vc * 32 + kgp * 8];
#pragma unroll
        for (int fb = 0; fb < 8; ++fb) {
          const int c = wc * 128 + fb * 16 + fr;
          short8 bv = *(const short8*)&Ks[buf][c * 32 + ((kgp ^ (c & 3)) * 8)];
          oa[0][fb] = __builtin_amdgcn_mfma_f32_16x16x32_bf16(pa0, bv, oa[0][fb], 0, 0, 0);
          oa[1][fb] = __builtin_amdgcn_mfma_f32_16x16x32_bf16(pa1, bv, oa[1][fb], 0, 0, 0);
        }
      }
    }
  }
#undef LOADK
#undef LOADV
#undef WRITEK
#undef WRITEV

  // l reduction across the 4 wc-waves
  if (fr == 0) {
#pragma unroll
    for (int r = 0; r < 4; ++r) {
      lred[wq][kgp * 4 + r][wc] = racc0[r];
      lred[wq][16 + kgp * 4 + r][wc] = racc1[r];
    }
  }
  __syncthreads();
  if (t < 64) {
    float s = lred[t >> 5][t & 31][0] + lred[t >> 5][t & 31][1] +
              lred[t >> 5][t & 31][2] + lred[t >> 5][t & 31][3];
    linv[t] = 1.f / s;
  }
  __syncthreads();
  // scale + transpose-stage O into Qs (Q dead), then coalesced store
#pragma unroll
  for (int i = 0; i < 2; ++i) {
    f32x4 li = *(const f32x4*)&linv[wq * 32 + i * 16 + kgp * 4];
#pragma unroll
    for (int fb = 0; fb < 8; ++fb) {
#pragma unroll
      for (int r = 0; r < 4; ++r)
        Qs[(wq * 32 + i * 16 + kgp * 4 + r) * 520 + wc * 128 + fb * 16 + fr] =
            f2bf(oa[i][fb][r] * li[r]);
    }
  }
  __syncthreads();
  {
    const int row = t >> 3, c0 = (t & 7) * 64;
    unsigned short* dst = og + (size_t)bz * BS + ((size_t)qt * 64 + row) * CCH + c0;
#pragma unroll
    for (int i = 0; i < 8; ++i)
      *(short8*)(dst + i * 8) = *(const short8*)&Qs[row * 520 + c0 + i * 8];
  }
}

extern "C" void kernel_launch(void* const* d_in, const int* in_sizes, int n_in,
                              void* d_out, int out_size, void* d_ws, size_t ws_size,
                              hipStream_t stream) {
  const float* x = (const float*)d_in[0];
  const float* gnw = (const float*)d_in[1];
  const float* gnb = (const float*)d_in[2];
  const float* wq = (const float*)d_in[3];
  const float* bq = (const float*)d_in[4];
  const float* wk = (const float*)d_in[5];
  const float* bk = (const float*)d_in[6];
  const float* wv = (const float*)d_in[7];
  const float* bv = (const float*)d_in[8];
  const float* wp = (const float*)d_in[9];
  const float* bp = (const float*)d_in[10];
  float* out = (float*)d_out;

  const size_t BS = (size_t)NPIX * CCH;

  char* ws = (char*)d_ws;
  float* stats = (float*)ws;
  unsigned short* hT = (unsigned short*)(ws + 1024);
  unsigned short* Abuf = hT;  // aliases hT (dead after v-GEMM)
  unsigned short* qb = hT + BATCH * BS;
  unsigned short* kTb = qb + BATCH * BS;
  unsigned short* vb = kTb + BATCH * BS;
  unsigned short* wqb = vb + BATCH * BS;
  unsigned short* wkb = wqb + CCH * CCH;
  unsigned short* wvb = wkb + CCH * CCH;
  unsigned short* wpb = wvb + CCH * CCH;
  size_t need = (size_t)((char*)(wpb + CCH * CCH) - ws);
  if (ws_size < need) return;

  f32_to_bf16<<<256, 256, 0, stream>>>(wq, wqb, CCH * CCH / 4);
  f32_to_bf16<<<256, 256, 0, stream>>>(wk, wkb, CCH * CCH / 4);
  f32_to_bf16<<<256, 256, 0, stream>>>(wv, wvb, CCH * CCH / 4);
  f32_to_bf16<<<256, 256, 0, stream>>>(wp, wpb, CCH * CCH / 4);

  gn_stats<<<BATCH * NGRP, 256, 0, stream>>>(x, stats);
  gn_apply_t<<<dim3(NPIX / 64, CCH / 64, BATCH), 256, 0, stream>>>(x, stats, gnw,
                                                                   gnb, hT);

  // q[n,o] = sum_c hT[n,c] wq[o,c] + bq[o]
  gemm_bt<2, 1, 0, 2><<<dim3(4, 32, BATCH), 256, 0, stream>>>(
      hT, wqb, qb, bq, nullptr, NPIX, CCH, CCH, CCH, CCH, CCH, (long)BS, 0,
      (long)BS, 0, 1.f);
  // kT[m,o] = sum_c hT[m,c] wk[o,c] + bk[o]
  gemm_bt<2, 1, 0, 2><<<dim3(4, 32, BATCH), 256, 0, stream>>>(
      hT, wkb, kTb, bk, nullptr, NPIX, CCH, CCH, CCH, CCH, CCH, (long)BS, 0,
      (long)BS, 0, 1.f);
  // v[c,m] = sum_c' wv[c,c'] hT[m,c'] + bv[c]
  gemm_bt<1, 1, 0, 0><<<dim3(4, 32, BATCH), 256, 0, stream>>>(
      wvb, hT, vb, bv, nullptr, CCH, NPIX, CCH, CCH, CCH, NPIX, 0, (long)BS,
      (long)BS, 0, 1.f);

  const float sscale = 0.044194173824159216f;  // 512^-0.5
  // fused attention: AoutT[q,c] per batch, written to Abuf (n,c)
  attn_fused<<<BATCH * 64, 512, 0, stream>>>(qb, kTb, vb, Abuf, sscale);

  // out[o,n] = sum_c wp[o,c] AoutT[n,c] + bp[o] + x[b,o,n]
  gemm_bt<1, 0, 1, 0><<<dim3(4, 32, BATCH), 256, 0, stream>>>(
      wpb, Abuf, out, bp, x, CCH, NPIX, CCH, CCH, CCH, NPIX, 0, (long)BS,
      (long)BS, (long)BS, 1.f);
}